// Round 1
// baseline (403.515 us; speedup 1.0000x reference)
//
#include <hip/hip_runtime.h>

// ---------------------------------------------------------------------------
// AttentionHead: out = softmax(mask(q k^T / sqrt(384))) v, q/k/v = x @ W{q,k,v}
// B=256, T=256, C=384, H=64.
// Kernel 1: QKV projection (bf16 MFMA), writes q (pre-scaled), k, v^T to ws.
// Kernel 2: per-batch attention, 1 block/batch, barrier-free, MFMA QK^T + PV.
// ---------------------------------------------------------------------------

typedef short s16x8 __attribute__((ext_vector_type(8)));   // 8 x bf16 (as raw bits)
typedef float f32x4 __attribute__((ext_vector_type(4)));

#define MFMA16(a, b, c) __builtin_amdgcn_mfma_f32_16x16x32_bf16((a), (b), (c), 0, 0, 0)

__device__ __forceinline__ unsigned short f2bf(float f) {
  unsigned u = __builtin_bit_cast(unsigned, f);
  u += 0x7fffu + ((u >> 16) & 1u);            // RNE; inputs are finite
  return (unsigned short)(u >> 16);
}

// ---------------------------------------------------------------------------
// Kernel 1: rows = B*T = 65536, K = 384, N = 192 (q|k|v).
// Block: 256 thr (4 waves), 64 rows/block -> grid 1024.
// Each wave: 16 rows x 192 cols = 12 MFMA tiles (f32x4 acc each).
// W chunk (32 x 192) staged in LDS column-major bf16 -> ds_read_b128 B-frags.
// ---------------------------------------------------------------------------
__global__ __launch_bounds__(256) void qkv_proj(
    const float* __restrict__ x, const float* __restrict__ Wq,
    const float* __restrict__ Wk, const float* __restrict__ Wv,
    unsigned short* __restrict__ qo, unsigned short* __restrict__ ko,
    unsigned short* __restrict__ vto) {
  __shared__ unsigned short Wc[192 * 32];  // [n][k] column-major, 12 KB
  const int tid = threadIdx.x;
  const int lane = tid & 63;
  const int wv = tid >> 6;
  const int n15 = lane & 15;
  const int q4 = lane >> 4;
  const long row0 = (long)blockIdx.x * 64 + wv * 16;

  f32x4 acc[12];
#pragma unroll
  for (int i = 0; i < 12; ++i) acc[i] = (f32x4){0.f, 0.f, 0.f, 0.f};

  for (int kc = 0; kc < 12; ++kc) {
    __syncthreads();  // protect Wc against previous iteration's readers
#pragma unroll
    for (int it = 0; it < 24; ++it) {
      int idx = tid + it * 256;       // 32*192 = 6144 elements
      int kk = idx / 192;
      int nn = idx - kk * 192;
      float val = (nn < 64)  ? Wq[(kc * 32 + kk) * 64 + nn]
                : (nn < 128) ? Wk[(kc * 32 + kk) * 64 + (nn - 64)]
                             : Wv[(kc * 32 + kk) * 64 + (nn - 128)];
      Wc[nn * 32 + kk] = f2bf(val);
    }
    __syncthreads();

    // A-frag: x[row0 + n15][kc*32 + q4*8 .. +7], 32B coalesced fp32 -> bf16
    const float* xp = x + (row0 + n15) * 384 + kc * 32 + q4 * 8;
    float4 x0 = *reinterpret_cast<const float4*>(xp);
    float4 x1 = *reinterpret_cast<const float4*>(xp + 4);
    s16x8 a;
    a[0] = (short)f2bf(x0.x); a[1] = (short)f2bf(x0.y);
    a[2] = (short)f2bf(x0.z); a[3] = (short)f2bf(x0.w);
    a[4] = (short)f2bf(x1.x); a[5] = (short)f2bf(x1.y);
    a[6] = (short)f2bf(x1.z); a[7] = (short)f2bf(x1.w);

#pragma unroll
    for (int nt = 0; nt < 12; ++nt) {
      s16x8 bb = *reinterpret_cast<const s16x8*>(&Wc[(nt * 16 + n15) * 32 + q4 * 8]);
      acc[nt] = MFMA16(a, bb, acc[nt]);
    }
  }

  // Epilogue: C-layout row = q4*4+e, col = nt*16+n15. nt<4 -> q, <8 -> k, else v^T
  const float qscale = 0.05103103630798287f;  // 1/sqrt(384), folded into q
#pragma unroll
  for (int nt = 0; nt < 12; ++nt) {
#pragma unroll
    for (int e = 0; e < 4; ++e) {
      long row = row0 + q4 * 4 + e;
      int col = nt * 16 + n15;
      float v = acc[nt][e];
      if (nt < 4) {
        qo[row * 64 + col] = f2bf(v * qscale);
      } else if (nt < 8) {
        ko[row * 64 + (col - 64)] = f2bf(v);
      } else {
        int h = col - 128;
        long bb_ = row >> 8;       // batch
        int t = (int)(row & 255);  // position in batch
        vto[(bb_ * 64 + h) * 256 + t] = f2bf(v);  // v transposed: [b][h][s]
      }
    }
  }
}

// ---------------------------------------------------------------------------
// Kernel 2: one block per batch. 4 waves; wave w handles q-tiles {w, w+4, w+8,
// w+12} (ascending -> P tail columns stay zero from the one-time init).
// Full score row held in registers (<=16 f32x4 tiles), softmax via quad-group
// shuffles, P -> per-wave LDS (bf16, A-frag layout), PV via MFMA with V/K/Q
// fragments read directly from L2-resident global. No __syncthreads at all.
// ---------------------------------------------------------------------------
__global__ __launch_bounds__(256) void attn(
    const unsigned short* __restrict__ q, const unsigned short* __restrict__ k,
    const unsigned short* __restrict__ vt, float* __restrict__ out) {
  __shared__ unsigned short Ps[4][16 * 264];  // per-wave P, row stride 264 (pad 8)
  const int b = blockIdx.x;
  const int tid = threadIdx.x;
  const int wv = tid >> 6;
  const int lane = tid & 63;
  const int n15 = lane & 15;
  const int q4 = lane >> 4;

  unsigned short* pbuf = &Ps[wv][0];
  for (int i = lane; i < 16 * 264; i += 64) pbuf[i] = 0;  // once; tails read 0

  const unsigned short* qb = q + b * 256 * 64;
  const unsigned short* kb = k + b * 256 * 64;
  const unsigned short* vb = vt + b * 64 * 256;

  for (int it = 0; it < 4; ++it) {
    const int qt = wv + it * 4;  // q-tile 0..15, wave-uniform, ascending
    // Q A-frags: A[m=n15][k=q4*8+j], two 32-wide k-chunks
    const s16x8 qf0 = *reinterpret_cast<const s16x8*>(qb + (qt * 16 + n15) * 64 + q4 * 8);
    const s16x8 qf1 = *reinterpret_cast<const s16x8*>(qb + (qt * 16 + n15) * 64 + 32 + q4 * 8);

    f32x4 S[16];
    float mx[4] = {-1e30f, -1e30f, -1e30f, -1e30f};
#pragma unroll 16
    for (int ct = 0; ct < 16; ++ct) {
      if (ct > qt) break;  // causal: skip tiles right of the diagonal
      // K^T B-frag: B[k=h][n=krow] = K[ct*16+n15][h], 16B contiguous
      s16x8 kf0 = *reinterpret_cast<const s16x8*>(kb + (ct * 16 + n15) * 64 + q4 * 8);
      s16x8 kf1 = *reinterpret_cast<const s16x8*>(kb + (ct * 16 + n15) * 64 + 32 + q4 * 8);
      f32x4 a = (f32x4){0.f, 0.f, 0.f, 0.f};
      a = MFMA16(qf0, kf0, a);
      a = MFMA16(qf1, kf1, a);
      if (ct == qt) {  // diagonal tile: mask col > row
#pragma unroll
        for (int e = 0; e < 4; ++e)
          if (n15 > q4 * 4 + e) a[e] = -1e30f;
      }
      S[ct] = a;
#pragma unroll
      for (int e = 0; e < 4; ++e) mx[e] = fmaxf(mx[e], a[e]);
    }
    // row max / sum live across the 16 lanes of each quad group (xor<16 stays in group)
#pragma unroll
    for (int off = 1; off < 16; off <<= 1)
#pragma unroll
      for (int e = 0; e < 4; ++e) mx[e] = fmaxf(mx[e], __shfl_xor(mx[e], off));

    float sm[4] = {0.f, 0.f, 0.f, 0.f};
#pragma unroll 16
    for (int ct = 0; ct < 16; ++ct) {
      if (ct > qt) break;
#pragma unroll
      for (int e = 0; e < 4; ++e) {
        float p = __expf(S[ct][e] - mx[e]);
        S[ct][e] = p;
        sm[e] += p;
      }
    }
#pragma unroll
    for (int off = 1; off < 16; off <<= 1)
#pragma unroll
      for (int e = 0; e < 4; ++e) sm[e] += __shfl_xor(sm[e], off);
    float rn[4];
#pragma unroll
    for (int e = 0; e < 4; ++e) rn[e] = 1.0f / sm[e];

    // P (C-layout) -> LDS row-major [m][s] bf16 for A-frag reads
#pragma unroll 16
    for (int ct = 0; ct < 16; ++ct) {
      if (ct > qt) break;
#pragma unroll
      for (int e = 0; e < 4; ++e)
        pbuf[(q4 * 4 + e) * 264 + ct * 16 + n15] = f2bf(S[ct][e]);
    }

    // O = P @ V
    f32x4 O[4];
#pragma unroll
    for (int nt = 0; nt < 4; ++nt) O[nt] = (f32x4){0.f, 0.f, 0.f, 0.f};
    const int nk = (qt + 2) >> 1;  // ceil(16*(qt+1)/32)
#pragma unroll 8
    for (int kc = 0; kc < 8; ++kc) {
      if (kc >= nk) break;
      s16x8 pf = *reinterpret_cast<const s16x8*>(pbuf + n15 * 264 + kc * 32 + q4 * 8);
#pragma unroll
      for (int nt = 0; nt < 4; ++nt) {
        // V B-frag: B[k=s][n=h] = vt[b][nt*16+n15][s], 16B contiguous
        s16x8 vf = *reinterpret_cast<const s16x8*>(vb + (nt * 16 + n15) * 256 + kc * 32 + q4 * 8);
        O[nt] = MFMA16(pf, vf, O[nt]);
      }
    }
    // normalize rows and write fp32 output
#pragma unroll
    for (int nt = 0; nt < 4; ++nt)
#pragma unroll
      for (int e = 0; e < 4; ++e)
        out[(size_t)(b * 256 + qt * 16 + q4 * 4 + e) * 64 + nt * 16 + n15] = O[nt][e] * rn[e];
  }
}

extern "C" void kernel_launch(void* const* d_in, const int* in_sizes, int n_in,
                              void* d_out, int out_size, void* d_ws, size_t ws_size,
                              hipStream_t stream) {
  const float* x  = (const float*)d_in[0];
  const float* Wq = (const float*)d_in[1];
  const float* Wk = (const float*)d_in[2];
  const float* Wv = (const float*)d_in[3];
  float* out = (float*)d_out;

  // ws layout: q | k | v^T, each 65536*64 bf16 (8 MB each, 25.2 MB total)
  unsigned short* qo  = (unsigned short*)d_ws;
  unsigned short* ko  = qo + (size_t)65536 * 64;
  unsigned short* vto = ko + (size_t)65536 * 64;

  qkv_proj<<<1024, 256, 0, stream>>>(x, Wq, Wk, Wv, qo, ko, vto);
  attn<<<256, 256, 0, stream>>>(qo, ko, vto, out);
}

// Round 2
// 235.164 us; speedup vs baseline: 1.7159x; 1.7159x over previous
//
#include <hip/hip_runtime.h>

// ---------------------------------------------------------------------------
// AttentionHead: out = softmax(mask(q k^T / sqrt(384))) v, q/k/v = x @ W{q,k,v}
// B=256, T=256, C=384, H=64.
// Kernel 0: W (fp32 [384][64] x3) -> Wt (bf16 [192][384], q part pre-scaled).
// Kernel 1: QKV projection, LDS-free: B-frags from L2-resident Wt.
// Kernel 2: attention, 4 blocks/batch, 1 q-tile/wave, balanced, barrier-free.
// ---------------------------------------------------------------------------

typedef short s16x8 __attribute__((ext_vector_type(8)));   // 8 x bf16 raw bits
typedef float f32x4 __attribute__((ext_vector_type(4)));

#define MFMA16(a, b, c) __builtin_amdgcn_mfma_f32_16x16x32_bf16((a), (b), (c), 0, 0, 0)

__device__ __forceinline__ unsigned short f2bf(float f) {
  unsigned u = __builtin_bit_cast(unsigned, f);
  u += 0x7fffu + ((u >> 16) & 1u);            // RNE; inputs finite
  return (unsigned short)(u >> 16);
}

// ---------------------------------------------------------------------------
// Kernel 0: Wt[n][k] = W_sel[k][n&63] (bf16), n<64 rows pre-scaled by 1/sqrt(384)
// ---------------------------------------------------------------------------
__global__ __launch_bounds__(256) void wcvt(
    const float* __restrict__ Wq, const float* __restrict__ Wk,
    const float* __restrict__ Wv, unsigned short* __restrict__ Wt) {
  int idx = blockIdx.x * 256 + threadIdx.x;   // 73728 = 192*384
  int n = idx / 384;
  int kk = idx - n * 384;
  const float* src = (n < 64) ? Wq : (n < 128) ? Wk : Wv;
  float v = src[kk * 64 + (n & 63)];
  if (n < 64) v *= 0.05103103630798287f;      // fold 1/sqrt(384) into Wq
  Wt[idx] = f2bf(v);
}

// ---------------------------------------------------------------------------
// Kernel 1: rows = 65536, K = 384, N = 192 (q|k|v). 512 blocks x 4 waves.
// Each wave: 2 row-tiles (32 rows) x 12 n-tiles. No LDS, no barriers.
// B-frag: Wt[(nt*16+n15)*384 + kc*32 + q4*8], 16B contiguous, L2-resident.
// ---------------------------------------------------------------------------
__global__ __launch_bounds__(256) void qkv_proj(
    const float* __restrict__ x, const unsigned short* __restrict__ Wt,
    unsigned short* __restrict__ qo, unsigned short* __restrict__ ko,
    unsigned short* __restrict__ vto) {
  const int tid = threadIdx.x;
  const int lane = tid & 63;
  const int wv = tid >> 6;
  const int n15 = lane & 15;
  const int q4 = lane >> 4;
  const long row0 = (long)blockIdx.x * 128 + wv * 32;

  f32x4 acc[2][12];
#pragma unroll
  for (int t = 0; t < 2; ++t)
#pragma unroll
    for (int i = 0; i < 12; ++i) acc[t][i] = (f32x4){0.f, 0.f, 0.f, 0.f};

  for (int kc = 0; kc < 12; ++kc) {
    s16x8 a[2];
#pragma unroll
    for (int t = 0; t < 2; ++t) {
      const float* xp = x + (row0 + t * 16 + n15) * 384 + kc * 32 + q4 * 8;
      float4 x0 = *reinterpret_cast<const float4*>(xp);
      float4 x1 = *reinterpret_cast<const float4*>(xp + 4);
      a[t][0] = (short)f2bf(x0.x); a[t][1] = (short)f2bf(x0.y);
      a[t][2] = (short)f2bf(x0.z); a[t][3] = (short)f2bf(x0.w);
      a[t][4] = (short)f2bf(x1.x); a[t][5] = (short)f2bf(x1.y);
      a[t][6] = (short)f2bf(x1.z); a[t][7] = (short)f2bf(x1.w);
    }
#pragma unroll
    for (int nt = 0; nt < 12; ++nt) {
      s16x8 bb = *reinterpret_cast<const s16x8*>(Wt + (nt * 16 + n15) * 384 + kc * 32 + q4 * 8);
      acc[0][nt] = MFMA16(a[0], bb, acc[0][nt]);
      acc[1][nt] = MFMA16(a[1], bb, acc[1][nt]);
    }
  }

  // Epilogue: C-layout row = q4*4+e, col = nt*16+n15. nt<4 -> q, <8 -> k, else v^T
#pragma unroll
  for (int t = 0; t < 2; ++t) {
#pragma unroll
    for (int nt = 0; nt < 12; ++nt) {
#pragma unroll
      for (int e = 0; e < 4; ++e) {
        long row = row0 + t * 16 + q4 * 4 + e;
        int col = nt * 16 + n15;
        unsigned short bv = f2bf(acc[t][nt][e]);
        if (nt < 4) {
          qo[row * 64 + col] = bv;             // q already scaled via Wt
        } else if (nt < 8) {
          ko[row * 64 + (col - 64)] = bv;
        } else {
          int h = col - 128;
          long bb_ = row >> 8;
          int tt = (int)(row & 255);
          vto[(bb_ * 64 + h) * 256 + tt] = bv; // v transposed: [b][h][s]
        }
      }
    }
  }
}

// ---------------------------------------------------------------------------
// Kernel 2: grid 1024 = 4 sub-blocks x 256 batches (batch = blockIdx & 255 so
// same-batch blocks share an XCD under %8 round-robin). Wave w of sub-block j
// handles q-tile {j, 7-j, 8+j, 15-j}[w] — every block sums to equal work.
// Scores in registers, quad-group shuffle softmax, P via per-wave LDS,
// K-frag 1-deep prefetch. No __syncthreads anywhere.
// ---------------------------------------------------------------------------
__global__ __launch_bounds__(256) void attn(
    const unsigned short* __restrict__ q, const unsigned short* __restrict__ k,
    const unsigned short* __restrict__ vt, float* __restrict__ out) {
  __shared__ unsigned short Ps[4][16 * 264];  // per-wave P, row stride 264
  const int b = blockIdx.x & 255;
  const int j = blockIdx.x >> 8;              // 0..3
  const int tid = threadIdx.x;
  const int wv = tid >> 6;
  const int lane = tid & 63;
  const int n15 = lane & 15;
  const int q4 = lane >> 4;

  const int qt = (wv == 0) ? j : (wv == 1) ? 7 - j : (wv == 2) ? 8 + j : 15 - j;

  unsigned short* pbuf = &Ps[wv][0];
  if (!(qt & 1)) {  // odd tile count -> zero the single tail 16x16 tile
    int r = lane >> 2, c = lane & 3;
    *reinterpret_cast<uint2*>(pbuf + r * 264 + (qt + 1) * 16 + c * 4) = make_uint2(0u, 0u);
  }

  const unsigned short* qb = q + b * 256 * 64;
  const unsigned short* kb = k + b * 256 * 64;
  const unsigned short* vb = vt + b * 64 * 256;

  const s16x8 qf0 = *reinterpret_cast<const s16x8*>(qb + (qt * 16 + n15) * 64 + q4 * 8);
  const s16x8 qf1 = *reinterpret_cast<const s16x8*>(qb + (qt * 16 + n15) * 64 + 32 + q4 * 8);

  f32x4 S[16];
  float mx[4] = {-1e30f, -1e30f, -1e30f, -1e30f};
  s16x8 kf0 = *reinterpret_cast<const s16x8*>(kb + n15 * 64 + q4 * 8);
  s16x8 kf1 = *reinterpret_cast<const s16x8*>(kb + n15 * 64 + 32 + q4 * 8);
#pragma unroll 16
  for (int ct = 0; ct < 16; ++ct) {
    if (ct > qt) break;
    const int nc = (ct < qt) ? ct + 1 : ct;   // clamped prefetch (in-bounds)
    s16x8 nf0 = *reinterpret_cast<const s16x8*>(kb + (nc * 16 + n15) * 64 + q4 * 8);
    s16x8 nf1 = *reinterpret_cast<const s16x8*>(kb + (nc * 16 + n15) * 64 + 32 + q4 * 8);
    f32x4 a = (f32x4){0.f, 0.f, 0.f, 0.f};
    a = MFMA16(qf0, kf0, a);
    a = MFMA16(qf1, kf1, a);
    if (ct == qt) {  // diagonal: mask col > row
#pragma unroll
      for (int e = 0; e < 4; ++e)
        if (n15 > q4 * 4 + e) a[e] = -1e30f;
    }
    S[ct] = a;
#pragma unroll
    for (int e = 0; e < 4; ++e) mx[e] = fmaxf(mx[e], a[e]);
    kf0 = nf0; kf1 = nf1;
  }
#pragma unroll
  for (int off = 1; off < 16; off <<= 1)
#pragma unroll
    for (int e = 0; e < 4; ++e) mx[e] = fmaxf(mx[e], __shfl_xor(mx[e], off));

  float sm[4] = {0.f, 0.f, 0.f, 0.f};
#pragma unroll 16
  for (int ct = 0; ct < 16; ++ct) {
    if (ct > qt) break;
#pragma unroll
    for (int e = 0; e < 4; ++e) {
      float p = __expf(S[ct][e] - mx[e]);
      S[ct][e] = p;
      sm[e] += p;
    }
  }
#pragma unroll
  for (int off = 1; off < 16; off <<= 1)
#pragma unroll
    for (int e = 0; e < 4; ++e) sm[e] += __shfl_xor(sm[e], off);
  float rn[4];
#pragma unroll
  for (int e = 0; e < 4; ++e) rn[e] = 1.0f / sm[e];

  // P (C-layout) -> LDS row-major [m][s] bf16 (A-frag reads below)
#pragma unroll 16
  for (int ct = 0; ct < 16; ++ct) {
    if (ct > qt) break;
#pragma unroll
    for (int e = 0; e < 4; ++e)
      pbuf[(q4 * 4 + e) * 264 + ct * 16 + n15] = f2bf(S[ct][e]);
  }

  // O = P @ V
  f32x4 O[4];
#pragma unroll
  for (int nt = 0; nt < 4; ++nt) O[nt] = (f32x4){0.f, 0.f, 0.f, 0.f};
  const int nk = (qt + 2) >> 1;  // ceil(16*(qt+1)/32)
#pragma unroll 8
  for (int kc = 0; kc < 8; ++kc) {
    if (kc >= nk) break;
    s16x8 pf = *reinterpret_cast<const s16x8*>(pbuf + n15 * 264 + kc * 32 + q4 * 8);
#pragma unroll
    for (int nt = 0; nt < 4; ++nt) {
      s16x8 vf = *reinterpret_cast<const s16x8*>(vb + (nt * 16 + n15) * 256 + kc * 32 + q4 * 8);
      O[nt] = MFMA16(pf, vf, O[nt]);
    }
  }
#pragma unroll
  for (int nt = 0; nt < 4; ++nt)
#pragma unroll
    for (int e = 0; e < 4; ++e)
      out[(size_t)(b * 256 + qt * 16 + q4 * 4 + e) * 64 + nt * 16 + n15] = O[nt][e] * rn[e];
}

extern "C" void kernel_launch(void* const* d_in, const int* in_sizes, int n_in,
                              void* d_out, int out_size, void* d_ws, size_t ws_size,
                              hipStream_t stream) {
  const float* x  = (const float*)d_in[0];
  const float* Wq = (const float*)d_in[1];
  const float* Wk = (const float*)d_in[2];
  const float* Wv = (const float*)d_in[3];
  float* out = (float*)d_out;

  // ws: q | k | v^T (each 65536*64 bf16 = 8 MB) | Wt (192*384 bf16 = 147 KB)
  unsigned short* qo  = (unsigned short*)d_ws;
  unsigned short* ko  = qo + (size_t)65536 * 64;
  unsigned short* vto = ko + (size_t)65536 * 64;
  unsigned short* Wt  = vto + (size_t)65536 * 64;

  wcvt<<<288, 256, 0, stream>>>(Wq, Wk, Wv, Wt);
  qkv_proj<<<512, 256, 0, stream>>>(x, Wt, qo, ko, vto);
  attn<<<1024, 256, 0, stream>>>(qo, ko, vto, out);
}